// Round 3
// baseline (307.565 us; speedup 1.0000x reference)
//
#include <hip/hip_runtime.h>
#include <stdint.h>

// Problem constants
#define BB 2
#define SS 2048
#define DD 1024
#define HH 16
#define DHD 64
#define MM (BB * SS)  // 4096

typedef unsigned short u16;
typedef unsigned int u32;
typedef __attribute__((ext_vector_type(8))) short bhalf8;   // 8 bf16 in 4 VGPRs
typedef __attribute__((ext_vector_type(4))) float floatx4;  // MFMA 16x16 accumulator
typedef __attribute__((ext_vector_type(2))) u32 u32x2;
typedef __attribute__((address_space(3))) u32 as3_u32;
typedef __attribute__((address_space(1))) u32 as1_u32;

__device__ __forceinline__ u16 f2bf(float f) {
  u32 u = __float_as_uint(f);
  u32 r = (u + 0x7FFFu + ((u >> 16) & 1u)) >> 16;  // RNE
  return (u16)r;
}

__device__ __forceinline__ u32 cvtpk_bf16(float lo, float hi) {
  u32 r;
  asm("v_cvt_pk_bf16_f32 %0, %1, %2" : "=v"(r) : "v"(lo), "v"(hi));
  return r;
}

// async global->LDS, 16B per lane; lds dest must be wave-uniform base (+lane*16 by HW)
__device__ __forceinline__ void gload16(const void* g, const void* l) {
  __builtin_amdgcn_global_load_lds((as1_u32*)(uintptr_t)g, (as3_u32*)(uintptr_t)l, 16, 0, 0);
}

// ---------------- fp32 -> bf16 elementwise convert (vectorized x4) ----------------
__global__ void k_convert(const float* __restrict__ in, u16* __restrict__ out, int n4) {
  int i = blockIdx.x * 256 + threadIdx.x;
  if (i < n4) {
    float4 v = ((const float4*)in)[i];
    ushort4 o;
    o.x = f2bf(v.x); o.y = f2bf(v.y); o.z = f2bf(v.z); o.w = f2bf(v.w);
    ((ushort4*)out)[i] = o;
  }
}

// ---------------- W[K][N] fp32 -> Wt[N][K] bf16 (tiled transpose) ----------------
__global__ void k_transpose_w(const float* __restrict__ W, u16* __restrict__ Wt) {
  __shared__ u16 tile[32][33];
  const int tx = threadIdx.x, ty = threadIdx.y;  // (32, 8)
  const int n0 = blockIdx.x * 32, k0 = blockIdx.y * 32;
#pragma unroll
  for (int i = 0; i < 4; ++i)
    tile[ty + 8 * i][tx] = f2bf(W[(size_t)(k0 + ty + 8 * i) * DD + n0 + tx]);
  __syncthreads();
#pragma unroll
  for (int i = 0; i < 4; ++i)
    Wt[(size_t)(n0 + ty + 8 * i) * DD + k0 + tx] = tile[tx][ty + 8 * i];
}

// ---------------- bf16 GEMM: C = A[M][K] * Bt[N][K]^T ----------------
// 128x128 tile, BK=32, 4 waves (2x2), 16x16x32 MFMA, global_load_lds double-buffer.
template <int MODE>
__global__ __launch_bounds__(256, 2) void k_gemm_bt(
    const u16* __restrict__ A, const u16* __restrict__ Bt, void* __restrict__ Cout,
    const int Ndim, const int Kdim, const float scale) {
  __shared__ __attribute__((aligned(16))) u16 sA[2][128 * 32];
  __shared__ __attribute__((aligned(16))) u16 sB[2][128 * 32];
  const int t = threadIdx.x;
  const int w = t >> 6, lane = t & 63;
  const int lr = lane & 15, lg = lane >> 4;
  const int wr = w >> 1, wc = w & 1;
  const int row0 = blockIdx.y * 128, col0 = blockIdx.x * 128;

  const int srow = t >> 2;         // staging row 0..63
  const int skoff = (t & 3) * 8;   // staging k element offset
  const u16* gA = A + (size_t)(row0 + srow) * Kdim + skoff;
  const u16* gB = Bt + (size_t)(col0 + srow) * Kdim + skoff;
  const int ldsbase = w * 512;     // wave-uniform LDS element base

  floatx4 acc[4][4] = {};

  auto stage = [&](int buf, int kt) {
    const int ko = kt * 32;
    gload16(gA + ko, &sA[buf][ldsbase]);
    gload16(gA + ko + (size_t)64 * Kdim, &sA[buf][2048 + ldsbase]);
    gload16(gB + ko, &sB[buf][ldsbase]);
    gload16(gB + ko + (size_t)64 * Kdim, &sB[buf][2048 + ldsbase]);
  };

  const int nk = Kdim / 32;
  int cur = 0;
  stage(0, 0);
  __syncthreads();
  for (int kt = 0; kt < nk; ++kt) {
    if (kt + 1 < nk) stage(cur ^ 1, kt + 1);
    bhalf8 af[4], bf[4];
#pragma unroll
    for (int m = 0; m < 4; ++m)
      af[m] = *(const bhalf8*)&sA[cur][(wr * 64 + m * 16 + lr) * 32 + lg * 8];
#pragma unroll
    for (int n = 0; n < 4; ++n)
      bf[n] = *(const bhalf8*)&sB[cur][(wc * 64 + n * 16 + lr) * 32 + lg * 8];
#pragma unroll
    for (int m = 0; m < 4; ++m)
#pragma unroll
      for (int n = 0; n < 4; ++n)
        acc[m][n] = __builtin_amdgcn_mfma_f32_16x16x32_bf16(af[m], bf[n], acc[m][n], 0, 0, 0);
    __syncthreads();
    cur ^= 1;
  }

#pragma unroll
  for (int m = 0; m < 4; ++m) {
#pragma unroll
    for (int n = 0; n < 4; ++n) {
      const int col = col0 + wc * 64 + n * 16 + lr;
      const int rowb = row0 + wr * 64 + m * 16 + lg * 4;
      if (MODE == 0) {
        u16* C = (u16*)Cout;
#pragma unroll
        for (int r = 0; r < 4; ++r)
          C[(size_t)(rowb + r) * Ndim + col] = f2bf(acc[m][n][r] * scale);
      } else if (MODE == 1) {
        // V^T layout: Vt[(b*1024 + col)][s], s = row % S, b = row / S; 4 rows contiguous
        u16* C = (u16*)Cout;
        const int bidx = rowb >> 11, s = rowb & (SS - 1);
        ushort4 pk;
        pk.x = f2bf(acc[m][n][0]); pk.y = f2bf(acc[m][n][1]);
        pk.z = f2bf(acc[m][n][2]); pk.w = f2bf(acc[m][n][3]);
        *(ushort4*)&C[((size_t)bidx * 1024 + col) * SS + s] = pk;
      } else {
        float* C = (float*)Cout;
#pragma unroll
        for (int r = 0; r < 4; ++r)
          C[(size_t)(rowb + r) * Ndim + col] = acc[m][n][r];
      }
    }
  }
}

// ---------------- flash attention v3 (swapped QK^T + wave-private LDS P) -------------
// grid (S/64, H, B), 256 threads = 4 waves, each wave owns 16 q-rows, KV tile = 64.
// Q pre-scaled by 1/8. K [B,S,D] bf16, Vt [B*H*64][S] bf16.
// Swapped QK^T: s = mfma(A=K, B=Q) -> s[c][r] = S[key = sk0+c*16+lg*4+r][q = q0+lr].
// Softmax stats live per-lane for q = lr (in-register tree + 2 shfl_xor).
// P goes through wave-private LDS (each lane writes its own q-row; no barriers,
// in-wave DS ordering + lgkmcnt(0)). PV reads the same A-fragment layout as v1.
__global__ __launch_bounds__(256, 2) void k_attn(
    const u16* __restrict__ Q, const u16* __restrict__ K, const u16* __restrict__ Vt,
    u16* __restrict__ O, const int* __restrict__ valid_lens) {
  const int t = threadIdx.x;
  const int w = t >> 6, lane = t & 63;
  const int lr = lane & 15, lg = lane >> 4;
  const int h = blockIdx.y, b = blockIdx.z;
  const int q0 = blockIdx.x * 64 + w * 16;
  const int vl = valid_lens[b];

  __shared__ __attribute__((aligned(16))) u16 p_lds[4][16 * 72];  // wave-private, stride 72
  u16* pl = &p_lds[w][0];

  const u16* Qp = Q + ((size_t)(b * SS + q0 + lr)) * DD + h * DHD;
  const bhalf8 qf0 = *(const bhalf8*)(Qp + lg * 8);
  const bhalf8 qf1 = *(const bhalf8*)(Qp + 32 + lg * 8);

  const u16* Kp = K + ((size_t)b * SS) * DD + h * DHD;
  const u16* Vp = Vt + ((size_t)(b * HH + h) * DHD) * SS;

  float mrun = -1e30f, lrun = 0.f;  // per-lane: stats of q-row (q0 + lr)
  floatx4 o[4] = {};                // o[dt]: C[q = lg*4+r][d = dt*16+lr]

  const int nblk = (vl + 63) >> 6;
  const bool partial = (vl & 63) != 0;

  auto loadK = [&](bhalf8(&kf)[4][2], int sk0) {
#pragma unroll
    for (int c = 0; c < 4; ++c) {
      const u16* kp = Kp + (size_t)(sk0 + c * 16 + lr) * DD;
      kf[c][0] = *(const bhalf8*)(kp + lg * 8);
      kf[c][1] = *(const bhalf8*)(kp + 32 + lg * 8);
    }
  };

  auto step = [&](bhalf8(&kc)[4][2], bhalf8(&kn)[4][2], int i) {
    const int sk0 = i * 64;
    // QK^T (swapped): s[c][r] = score[key = sk0+c*16+lg*4+r][q = q0+lr]
    floatx4 s[4];
#pragma unroll
    for (int c = 0; c < 4; ++c) {
      floatx4 z = {0.f, 0.f, 0.f, 0.f};
      z = __builtin_amdgcn_mfma_f32_16x16x32_bf16(kc[c][0], qf0, z, 0, 0, 0);
      s[c] = __builtin_amdgcn_mfma_f32_16x16x32_bf16(kc[c][1], qf1, z, 0, 0, 0);
    }
    // prefetch next K tile (register double-buffer)
    if (i + 1 < nblk) loadK(kn, sk0 + 64);
    // V loads for current tile, issued before softmax so latency hides under VALU
    bhalf8 vf0[4], vf1[4];
#pragma unroll
    for (int dt = 0; dt < 4; ++dt) {
      const u16* vp = Vp + (size_t)(dt * 16 + lr) * SS + sk0 + lg * 8;
      vf0[dt] = *(const bhalf8*)(vp);
      vf1[dt] = *(const bhalf8*)(vp + 32);
    }
    // mask tail keys (uniform branch; key index is per-reg)
    if (partial && i == nblk - 1) {
#pragma unroll
      for (int c = 0; c < 4; ++c)
#pragma unroll
        for (int r = 0; r < 4; ++r)
          if (sk0 + c * 16 + lg * 4 + r >= vl) s[c][r] = -1e6f;
    }
    // row max: in-register tree + 2 cross-lane steps (lanes sharing lr)
    float tmax = fmaxf(fmaxf(fmaxf(s[0][0], s[0][1]), fmaxf(s[0][2], s[0][3])),
                       fmaxf(fmaxf(s[1][0], s[1][1]), fmaxf(s[1][2], s[1][3])));
    tmax = fmaxf(tmax, fmaxf(fmaxf(fmaxf(s[2][0], s[2][1]), fmaxf(s[2][2], s[2][3])),
                             fmaxf(fmaxf(s[3][0], s[3][1]), fmaxf(s[3][2], s[3][3]))));
    tmax = fmaxf(tmax, __shfl_xor(tmax, 16));
    tmax = fmaxf(tmax, __shfl_xor(tmax, 32));
    // online-softmax rescale (every tile; sc==1.0 when max didn't grow)
    const float nm = fmaxf(mrun, tmax);
    const float sc = __expf(mrun - nm);
    mrun = nm;
    // p = exp(s - m), row sum, pack to bf16 pairs
    float rs = 0.f;
    u32 pk[4][2];
#pragma unroll
    for (int c = 0; c < 4; ++c) {
      float p0 = __expf(s[c][0] - nm), p1 = __expf(s[c][1] - nm);
      float p2 = __expf(s[c][2] - nm), p3 = __expf(s[c][3] - nm);
      rs += (p0 + p1) + (p2 + p3);
      pk[c][0] = cvtpk_bf16(p0, p1);
      pk[c][1] = cvtpk_bf16(p2, p3);
    }
    rs += __shfl_xor(rs, 16);
    rs += __shfl_xor(rs, 32);
    lrun = lrun * sc + rs;
    // rescale O (stats q=lr -> accum rows q=lg*4+r via shfl broadcast)
    float scb[4];
#pragma unroll
    for (int r = 0; r < 4; ++r) scb[r] = __shfl(sc, lg * 4 + r);
#pragma unroll
    for (int dt = 0; dt < 4; ++dt)
#pragma unroll
      for (int r = 0; r < 4; ++r) o[dt][r] *= scb[r];
    // P -> wave-private LDS: lane writes its own q-row (lr), keys c*16+lg*4..+3
#pragma unroll
    for (int c = 0; c < 4; ++c) {
      u32x2 pr; pr.x = pk[c][0]; pr.y = pk[c][1];
      *(u32x2*)&pl[lr * 72 + c * 16 + lg * 4] = pr;
    }
    asm volatile("s_waitcnt lgkmcnt(0)" ::: "memory");  // in-wave write->read ordering
    const bhalf8 pa0 = *(const bhalf8*)&pl[lr * 72 + lg * 8];
    const bhalf8 pa1 = *(const bhalf8*)&pl[lr * 72 + 32 + lg * 8];
    // PV: o[dt] += P * V
#pragma unroll
    for (int dt = 0; dt < 4; ++dt) {
      o[dt] = __builtin_amdgcn_mfma_f32_16x16x32_bf16(pa0, vf0[dt], o[dt], 0, 0, 0);
      o[dt] = __builtin_amdgcn_mfma_f32_16x16x32_bf16(pa1, vf1[dt], o[dt], 0, 0, 0);
    }
  };

  bhalf8 kbufA[4][2], kbufB[4][2];
  loadK(kbufA, 0);
  for (int i = 0; i < nblk; ++i) {
    if (i & 1) step(kbufB, kbufA, i);
    else       step(kbufA, kbufB, i);
  }

  // epilogue: normalize and store
  const float linv = 1.0f / lrun;  // per-lane (row q0+lr)
  float lb[4];
#pragma unroll
  for (int r = 0; r < 4; ++r) lb[r] = __shfl(linv, lg * 4 + r);
  u16* Op = O + ((size_t)(b * SS + q0)) * DD + h * DHD;
#pragma unroll
  for (int dt = 0; dt < 4; ++dt)
#pragma unroll
    for (int r = 0; r < 4; ++r)
      Op[(size_t)(lg * 4 + r) * DD + dt * 16 + lr] = f2bf(o[dt][r] * lb[r]);
}

extern "C" void kernel_launch(void* const* d_in, const int* in_sizes, int n_in,
                              void* d_out, int out_size, void* d_ws, size_t ws_size,
                              hipStream_t stream) {
  const float* q = (const float*)d_in[0];
  const float* k = (const float*)d_in[1];
  const float* v = (const float*)d_in[2];
  const int* vl = (const int*)d_in[3];
  const float* Wq = (const float*)d_in[4];
  const float* Wk = (const float*)d_in[5];
  const float* Wv = (const float*)d_in[6];
  const float* Wo = (const float*)d_in[7];

  char* ws = (char*)d_ws;
  u16* Xq  = (u16*)(ws + 0);          // 8 MiB each: bf16 inputs
  u16* Xk  = (u16*)(ws + 8388608);
  u16* Xv  = (u16*)(ws + 16777216);
  u16* Wtq = (u16*)(ws + 25165824);   // 2 MiB each: bf16 W^T
  u16* Wtk = (u16*)(ws + 27262976);
  u16* Wtv = (u16*)(ws + 29360128);
  u16* Wto = (u16*)(ws + 31457280);
  u16* Qb  = (u16*)(ws + 33554432);   // 8 MiB each: projected Q,K
  u16* Kb  = (u16*)(ws + 41943040);
  u16* Vtb = (u16*)(ws + 50331648);   // 8 MiB: head-transposed V
  u16* Ob  = (u16*)(ws + 58720256);   // 8 MiB: attention output (merged heads)

  const int n4 = (MM * DD) / 4;
  k_convert<<<4096, 256, 0, stream>>>(q, Xq, n4);
  k_convert<<<4096, 256, 0, stream>>>(k, Xk, n4);
  k_convert<<<4096, 256, 0, stream>>>(v, Xv, n4);

  dim3 tb(32, 8);
  k_transpose_w<<<dim3(32, 32), tb, 0, stream>>>(Wq, Wtq);
  k_transpose_w<<<dim3(32, 32), tb, 0, stream>>>(Wk, Wtk);
  k_transpose_w<<<dim3(32, 32), tb, 0, stream>>>(Wv, Wtv);
  k_transpose_w<<<dim3(32, 32), tb, 0, stream>>>(Wo, Wto);

  dim3 gg(DD / 128, MM / 128);  // (8, 32)
  k_gemm_bt<0><<<gg, 256, 0, stream>>>(Xq, Wtq, Qb, DD, DD, 0.125f);  // 1/sqrt(64) folded
  k_gemm_bt<0><<<gg, 256, 0, stream>>>(Xk, Wtk, Kb, DD, DD, 1.0f);
  k_gemm_bt<1><<<gg, 256, 0, stream>>>(Xv, Wtv, Vtb, DD, DD, 1.0f);

  k_attn<<<dim3(SS / 64, HH, BB), 256, 0, stream>>>(Qb, Kb, Vtb, Ob, vl);

  k_gemm_bt<2><<<gg, 256, 0, stream>>>(Ob, Wto, d_out, DD, DD, 1.0f);
}

// Round 4
// 282.885 us; speedup vs baseline: 1.0872x; 1.0872x over previous
//
#include <hip/hip_runtime.h>
#include <stdint.h>

// Problem constants
#define BB 2
#define SS 2048
#define DD 1024
#define HH 16
#define DHD 64
#define MM (BB * SS)  // 4096

typedef unsigned short u16;
typedef unsigned int u32;
typedef __attribute__((ext_vector_type(8))) short bhalf8;   // 8 bf16 in 4 VGPRs
typedef __attribute__((ext_vector_type(4))) float floatx4;  // MFMA 16x16 accumulator
typedef __attribute__((ext_vector_type(2))) u32 u32x2;
typedef __attribute__((address_space(3))) u32 as3_u32;
typedef __attribute__((address_space(1))) u32 as1_u32;

__device__ __forceinline__ u16 f2bf(float f) {
  u32 u = __float_as_uint(f);
  u32 r = (u + 0x7FFFu + ((u >> 16) & 1u)) >> 16;  // RNE
  return (u16)r;
}

__device__ __forceinline__ u32 cvtpk_bf16(float lo, float hi) {
  u32 r;
  asm("v_cvt_pk_bf16_f32 %0, %1, %2" : "=v"(r) : "v"(lo), "v"(hi));
  return r;
}

__device__ __forceinline__ float exp2_fast(float x) {  // v_exp_f32 computes 2^x
  float r;
  asm("v_exp_f32 %0, %1" : "=v"(r) : "v"(x));
  return r;
}

// async global->LDS, 16B per lane; lds dest must be wave-uniform base (+lane*16 by HW)
__device__ __forceinline__ void gload16(const void* g, const void* l) {
  __builtin_amdgcn_global_load_lds((as1_u32*)(uintptr_t)g, (as3_u32*)(uintptr_t)l, 16, 0, 0);
}

// ---------------- fused fp32 -> bf16 convert for q,k,v (z-indexed) ----------------
__global__ void k_convert3(const float* __restrict__ q, const float* __restrict__ k,
                           const float* __restrict__ v, u16* __restrict__ out) {
  const int z = blockIdx.y;
  const float* src = (z == 0) ? q : (z == 1) ? k : v;
  const int i = blockIdx.x * 256 + threadIdx.x;  // grid.x*256 == 4M/4 exactly
  float4 val = ((const float4*)src)[i];
  ushort4 o;
  o.x = f2bf(val.x); o.y = f2bf(val.y); o.z = f2bf(val.z); o.w = f2bf(val.w);
  ((ushort4*)(out + (size_t)z * 4194304))[i] = o;
}

// ---------------- fused W[K][N] fp32 -> Wt[N][K] bf16 (z-indexed, scaled) ----------
// z==0 (Wq) folds 1/sqrt(DH) * log2(e) so attention scores come out in log2 units.
__global__ void k_transpose4(const float* __restrict__ Wq, const float* __restrict__ Wk,
                             const float* __restrict__ Wv, const float* __restrict__ Wo,
                             u16* __restrict__ Wt) {
  const int z = blockIdx.z;
  const float* W = (z == 0) ? Wq : (z == 1) ? Wk : (z == 2) ? Wv : Wo;
  const float sc = (z == 0) ? 0.18033688011112042f : 1.0f;  // 0.125 * log2(e)
  __shared__ u16 tile[32][33];
  const int tx = threadIdx.x, ty = threadIdx.y;  // (32, 8)
  const int n0 = blockIdx.x * 32, k0 = blockIdx.y * 32;
#pragma unroll
  for (int i = 0; i < 4; ++i)
    tile[ty + 8 * i][tx] = f2bf(W[(size_t)(k0 + ty + 8 * i) * DD + n0 + tx] * sc);
  __syncthreads();
  u16* dst = Wt + (size_t)z * 1048576;
#pragma unroll
  for (int i = 0; i < 4; ++i)
    dst[(size_t)(n0 + ty + 8 * i) * DD + k0 + tx] = tile[tx][ty + 8 * i];
}

// ---------------- fused QKV GEMM: z selects A/Bt/C; 128x128 tile, BK=32 --------------
__global__ __launch_bounds__(256, 2) void k_gemm_qkv(
    const u16* __restrict__ Xq, const u16* __restrict__ Xk, const u16* __restrict__ Xv,
    const u16* __restrict__ Wt, u16* __restrict__ Qb, u16* __restrict__ Kb,
    u16* __restrict__ Vtb) {
  const int z = blockIdx.z;
  const u16* A = (z == 0) ? Xq : (z == 1) ? Xk : Xv;
  const u16* Bt = Wt + (size_t)z * 1048576;
  __shared__ __attribute__((aligned(16))) u16 sA[2][128 * 32];
  __shared__ __attribute__((aligned(16))) u16 sB[2][128 * 32];
  const int t = threadIdx.x;
  const int w = t >> 6, lane = t & 63;
  const int lr = lane & 15, lg = lane >> 4;
  const int wr = w >> 1, wc = w & 1;
  const int row0 = blockIdx.y * 128, col0 = blockIdx.x * 128;

  const int srow = t >> 2;
  const int skoff = (t & 3) * 8;
  const u16* gA = A + (size_t)(row0 + srow) * DD + skoff;
  const u16* gB = Bt + (size_t)(col0 + srow) * DD + skoff;
  const int ldsbase = w * 512;

  floatx4 acc[4][4] = {};

  auto stage = [&](int buf, int kt) {
    const int ko = kt * 32;
    gload16(gA + ko, &sA[buf][ldsbase]);
    gload16(gA + ko + (size_t)64 * DD, &sA[buf][2048 + ldsbase]);
    gload16(gB + ko, &sB[buf][ldsbase]);
    gload16(gB + ko + (size_t)64 * DD, &sB[buf][2048 + ldsbase]);
  };

  int cur = 0;
  stage(0, 0);
  __syncthreads();
  for (int kt = 0; kt < 32; ++kt) {
    if (kt + 1 < 32) stage(cur ^ 1, kt + 1);
    bhalf8 af[4], bf[4];
#pragma unroll
    for (int m = 0; m < 4; ++m)
      af[m] = *(const bhalf8*)&sA[cur][(wr * 64 + m * 16 + lr) * 32 + lg * 8];
#pragma unroll
    for (int n = 0; n < 4; ++n)
      bf[n] = *(const bhalf8*)&sB[cur][(wc * 64 + n * 16 + lr) * 32 + lg * 8];
#pragma unroll
    for (int m = 0; m < 4; ++m)
#pragma unroll
      for (int n = 0; n < 4; ++n)
        acc[m][n] = __builtin_amdgcn_mfma_f32_16x16x32_bf16(af[m], bf[n], acc[m][n], 0, 0, 0);
    __syncthreads();
    cur ^= 1;
  }

#pragma unroll
  for (int m = 0; m < 4; ++m) {
#pragma unroll
    for (int n = 0; n < 4; ++n) {
      const int col = col0 + wc * 64 + n * 16 + lr;
      const int rowb = row0 + wr * 64 + m * 16 + lg * 4;
      if (z == 2) {
        // V^T layout: Vtb[(b*1024 + col)][s]
        const int bidx = rowb >> 11, s = rowb & (SS - 1);
        ushort4 pk;
        pk.x = f2bf(acc[m][n][0]); pk.y = f2bf(acc[m][n][1]);
        pk.z = f2bf(acc[m][n][2]); pk.w = f2bf(acc[m][n][3]);
        *(ushort4*)&Vtb[((size_t)bidx * 1024 + col) * SS + s] = pk;
      } else {
        u16* C = (z == 0) ? Qb : Kb;
#pragma unroll
        for (int r = 0; r < 4; ++r)
          C[(size_t)(rowb + r) * DD + col] = f2bf(acc[m][n][r]);
      }
    }
  }
}

// ---------------- Wo GEMM: 64x128 tile (512 blocks, 2/CU), fp32 out ------------------
__global__ __launch_bounds__(256, 2) void k_gemm_wo(
    const u16* __restrict__ A, const u16* __restrict__ Bt, float* __restrict__ C) {
  __shared__ __attribute__((aligned(16))) u16 sA[2][64 * 32];
  __shared__ __attribute__((aligned(16))) u16 sB[2][128 * 32];
  const int t = threadIdx.x;
  const int w = t >> 6, lane = t & 63;
  const int lr = lane & 15, lg = lane >> 4;
  const int wr = w >> 1, wc = w & 1;
  const int row0 = blockIdx.y * 64, col0 = blockIdx.x * 128;

  const int srow = t >> 2;
  const int skoff = (t & 3) * 8;
  const u16* gA = A + (size_t)(row0 + srow) * DD + skoff;
  const u16* gB = Bt + (size_t)(col0 + srow) * DD + skoff;
  const int ldsbase = w * 512;

  floatx4 acc[2][4] = {};

  auto stage = [&](int buf, int kt) {
    const int ko = kt * 32;
    gload16(gA + ko, &sA[buf][ldsbase]);
    gload16(gB + ko, &sB[buf][ldsbase]);
    gload16(gB + ko + (size_t)64 * DD, &sB[buf][2048 + ldsbase]);
  };

  int cur = 0;
  stage(0, 0);
  __syncthreads();
  for (int kt = 0; kt < 32; ++kt) {
    if (kt + 1 < 32) stage(cur ^ 1, kt + 1);
    bhalf8 af[2], bf[4];
#pragma unroll
    for (int m = 0; m < 2; ++m)
      af[m] = *(const bhalf8*)&sA[cur][(wr * 32 + m * 16 + lr) * 32 + lg * 8];
#pragma unroll
    for (int n = 0; n < 4; ++n)
      bf[n] = *(const bhalf8*)&sB[cur][(wc * 64 + n * 16 + lr) * 32 + lg * 8];
#pragma unroll
    for (int m = 0; m < 2; ++m)
#pragma unroll
      for (int n = 0; n < 4; ++n)
        acc[m][n] = __builtin_amdgcn_mfma_f32_16x16x32_bf16(af[m], bf[n], acc[m][n], 0, 0, 0);
    __syncthreads();
    cur ^= 1;
  }

#pragma unroll
  for (int m = 0; m < 2; ++m)
#pragma unroll
    for (int n = 0; n < 4; ++n) {
      const int col = col0 + wc * 64 + n * 16 + lr;
      const int rowb = row0 + wr * 32 + m * 16 + lg * 4;
#pragma unroll
      for (int r = 0; r < 4; ++r)
        C[(size_t)(rowb + r) * DD + col] = acc[m][n][r];
    }
}

// ---------------- flash attention v4 (split-KV, swapped QK^T, exp2) ------------------
// grid (S/64, H, B*P), 256 threads = 4 waves, each wave owns 16 q-rows, KV tile = 64.
// Scores come out of MFMA already scaled by log2(e)/8 (folded into Wq).
// Writes UNNORMALIZED fp32 partial O + per-row (m, l) to be merged by k_merge.
__global__ __launch_bounds__(256, 2) void k_attn(
    const u16* __restrict__ Q, const u16* __restrict__ K, const u16* __restrict__ Vt,
    float* __restrict__ Opart, float2* __restrict__ Ml,
    const int* __restrict__ valid_lens, const int part) {
  const int t = threadIdx.x;
  const int w = t >> 6, lane = t & 63;
  const int lr = lane & 15, lg = lane >> 4;
  const int h = blockIdx.y;
  const int z = blockIdx.z;
  const int b = z & 1, p = z >> 1;
  const int q0 = blockIdx.x * 64 + w * 16;
  const int vl = valid_lens[b];
  const int kbeg = p * part;
  if (kbeg >= vl) return;  // dead partition (uniform)
  const int kend = (vl < kbeg + part) ? vl : (kbeg + part);
  const int L = kend - kbeg;

  __shared__ __attribute__((aligned(16))) u16 p_lds[4][16 * 72];  // wave-private
  u16* pl = &p_lds[w][0];

  const u16* Qp = Q + ((size_t)(b * SS + q0 + lr)) * DD + h * DHD;
  const bhalf8 qf0 = *(const bhalf8*)(Qp + lg * 8);
  const bhalf8 qf1 = *(const bhalf8*)(Qp + 32 + lg * 8);

  const u16* Kp = K + ((size_t)(b * SS + kbeg)) * DD + h * DHD;
  const u16* Vp = Vt + ((size_t)(b * HH + h) * DHD) * SS + kbeg;

  float mrun = -1e30f, lrun = 0.f;  // per-lane: stats of q-row (q0 + lr), log2 units
  floatx4 o[4] = {};                // o[dt]: C[q = lg*4+r][d = dt*16+lr]

  const int nblk = (L + 63) >> 6;
  const bool partial = (L & 63) != 0;

  auto loadK = [&](bhalf8(&kf)[4][2], int sk0) {
#pragma unroll
    for (int c = 0; c < 4; ++c) {
      const u16* kp = Kp + (size_t)(sk0 + c * 16 + lr) * DD;
      kf[c][0] = *(const bhalf8*)(kp + lg * 8);
      kf[c][1] = *(const bhalf8*)(kp + 32 + lg * 8);
    }
  };

  auto step = [&](bhalf8(&kc)[4][2], bhalf8(&kn)[4][2], int i) {
    const int sk0 = i * 64;
    floatx4 s[4];
    __builtin_amdgcn_s_setprio(1);
#pragma unroll
    for (int c = 0; c < 4; ++c) {
      floatx4 zz = {0.f, 0.f, 0.f, 0.f};
      zz = __builtin_amdgcn_mfma_f32_16x16x32_bf16(kc[c][0], qf0, zz, 0, 0, 0);
      s[c] = __builtin_amdgcn_mfma_f32_16x16x32_bf16(kc[c][1], qf1, s[c] = zz, 0, 0, 0);
    }
    __builtin_amdgcn_s_setprio(0);
    if (i + 1 < nblk) loadK(kn, sk0 + 64);
    bhalf8 vf0[4], vf1[4];
#pragma unroll
    for (int dt = 0; dt < 4; ++dt) {
      const u16* vp = Vp + (size_t)(dt * 16 + lr) * SS + sk0 + lg * 8;
      vf0[dt] = *(const bhalf8*)(vp);
      vf1[dt] = *(const bhalf8*)(vp + 32);
    }
    if (partial && i == nblk - 1) {
#pragma unroll
      for (int c = 0; c < 4; ++c)
#pragma unroll
        for (int r = 0; r < 4; ++r)
          if (sk0 + c * 16 + lg * 4 + r >= L) s[c][r] = -1e6f;
    }
    float tmax = fmaxf(fmaxf(fmaxf(s[0][0], s[0][1]), fmaxf(s[0][2], s[0][3])),
                       fmaxf(fmaxf(s[1][0], s[1][1]), fmaxf(s[1][2], s[1][3])));
    tmax = fmaxf(tmax, fmaxf(fmaxf(fmaxf(s[2][0], s[2][1]), fmaxf(s[2][2], s[2][3])),
                             fmaxf(fmaxf(s[3][0], s[3][1]), fmaxf(s[3][2], s[3][3]))));
    tmax = fmaxf(tmax, __shfl_xor(tmax, 16));
    tmax = fmaxf(tmax, __shfl_xor(tmax, 32));
    const float nm = fmaxf(mrun, tmax);
    const float sc = exp2_fast(mrun - nm);
    mrun = nm;
    float rs = 0.f;
    u32 pk[4][2];
#pragma unroll
    for (int c = 0; c < 4; ++c) {
      float p0 = exp2_fast(s[c][0] - nm), p1 = exp2_fast(s[c][1] - nm);
      float p2 = exp2_fast(s[c][2] - nm), p3 = exp2_fast(s[c][3] - nm);
      rs += (p0 + p1) + (p2 + p3);
      pk[c][0] = cvtpk_bf16(p0, p1);
      pk[c][1] = cvtpk_bf16(p2, p3);
    }
    rs += __shfl_xor(rs, 16);
    rs += __shfl_xor(rs, 32);
    lrun = lrun * sc + rs;
    float scb[4];
#pragma unroll
    for (int r = 0; r < 4; ++r) scb[r] = __shfl(sc, lg * 4 + r);
#pragma unroll
    for (int dt = 0; dt < 4; ++dt)
#pragma unroll
      for (int r = 0; r < 4; ++r) o[dt][r] *= scb[r];
#pragma unroll
    for (int c = 0; c < 4; ++c) {
      u32x2 pr; pr.x = pk[c][0]; pr.y = pk[c][1];
      *(u32x2*)&pl[lr * 72 + c * 16 + lg * 4] = pr;
    }
    asm volatile("s_waitcnt lgkmcnt(0)" ::: "memory");
    const bhalf8 pa0 = *(const bhalf8*)&pl[lr * 72 + lg * 8];
    const bhalf8 pa1 = *(const bhalf8*)&pl[lr * 72 + 32 + lg * 8];
    __builtin_amdgcn_s_setprio(1);
#pragma unroll
    for (int dt = 0; dt < 4; ++dt) {
      o[dt] = __builtin_amdgcn_mfma_f32_16x16x32_bf16(pa0, vf0[dt], o[dt], 0, 0, 0);
      o[dt] = __builtin_amdgcn_mfma_f32_16x16x32_bf16(pa1, vf1[dt], o[dt], 0, 0, 0);
    }
    __builtin_amdgcn_s_setprio(0);
  };

  bhalf8 kbufA[4][2], kbufB[4][2];
  loadK(kbufA, 0);
  for (int i = 0; i < nblk; ++i) {
    if (i & 1) step(kbufB, kbufA, i);
    else       step(kbufA, kbufB, i);
  }

  // epilogue: store unnormalized partial + (m, l)
  const size_t rowbase = ((size_t)(b * HH + h)) * SS + q0;
  const size_t pbase = (size_t)p * (BB * HH * SS);
#pragma unroll
  for (int dt = 0; dt < 4; ++dt)
#pragma unroll
    for (int r = 0; r < 4; ++r)
      Opart[(pbase + rowbase + lg * 4 + r) * DHD + dt * 16 + lr] = o[dt][r];
  if (lane < 16) {
    float2 ml; ml.x = mrun; ml.y = lrun;
    Ml[pbase + rowbase + lr] = ml;
  }
}

// ---------------- merge split-KV partials -> bf16 merged-head output -----------------
template <int P>
__global__ void k_merge(const float* __restrict__ Opart, const float2* __restrict__ Ml,
                        const int* __restrict__ valid_lens, u16* __restrict__ Ob) {
  const int t = threadIdx.x;
  const int rid = blockIdx.x * 16 + (t >> 4);  // [0, B*H*S)
  const int dc = t & 15;
  const int b = rid >> 15;
  const int h = (rid >> 11) & (HH - 1);
  const int s = rid & (SS - 1);
  const int vl = valid_lens[b];
  constexpr int part = SS / P;
  float m[P], l[P];
  float4 o4[P];
  bool live[P];
  float M = -1e30f;
#pragma unroll
  for (int p = 0; p < P; ++p) {
    live[p] = (p * part < vl);
    if (live[p]) {
      float2 ml = Ml[(size_t)p * (BB * HH * SS) + rid];
      m[p] = ml.x; l[p] = ml.y;
      o4[p] = *(const float4*)&Opart[((size_t)p * (BB * HH * SS) + rid) * DHD + dc * 4];
      M = fmaxf(M, m[p]);
    }
  }
  float L = 0.f;
  float4 acc = {0.f, 0.f, 0.f, 0.f};
#pragma unroll
  for (int p = 0; p < P; ++p)
    if (live[p]) {
      const float wgt = exp2_fast(m[p] - M);
      L += l[p] * wgt;
      acc.x += wgt * o4[p].x; acc.y += wgt * o4[p].y;
      acc.z += wgt * o4[p].z; acc.w += wgt * o4[p].w;
    }
  const float inv = 1.0f / L;
  ushort4 r;
  r.x = f2bf(acc.x * inv); r.y = f2bf(acc.y * inv);
  r.z = f2bf(acc.z * inv); r.w = f2bf(acc.w * inv);
  *(ushort4*)&Ob[((size_t)(b * SS + s)) * DD + h * DHD + dc * 4] = r;
}

extern "C" void kernel_launch(void* const* d_in, const int* in_sizes, int n_in,
                              void* d_out, int out_size, void* d_ws, size_t ws_size,
                              hipStream_t stream) {
  const float* q = (const float*)d_in[0];
  const float* k = (const float*)d_in[1];
  const float* v = (const float*)d_in[2];
  const int* vl = (const int*)d_in[3];
  const float* Wq = (const float*)d_in[4];
  const float* Wk = (const float*)d_in[5];
  const float* Wv = (const float*)d_in[6];
  const float* Wo = (const float*)d_in[7];

  char* ws = (char*)d_ws;
  u16* Xq  = (u16*)(ws + 0);          // 8 MiB each (dead after QKV GEMM)
  u16* Wtq = (u16*)(ws + 25165824);   // 2 MiB each: Wtq,Wtk,Wtv,Wto contiguous
  u16* Wto = (u16*)(ws + 31457280);
  u16* Qb  = (u16*)(ws + 33554432);   // 8 MiB each
  u16* Kb  = (u16*)(ws + 41943040);
  u16* Vtb = (u16*)(ws + 50331648);
  u16* Ob  = (u16*)(ws + 58720256);   // 8 MiB

  // split-KV partials: P=4 above 64MiB if workspace allows, else P=1 overlaying dead X
  const bool big = ws_size >= (size_t)134 * 1024 * 1024;
  const int P = big ? 4 : 1;
  const int part = SS / P;
  float* Opart = big ? (float*)(ws + 67108864) : (float*)(ws + 0);
  float2* Ml   = big ? (float2*)(ws + 67108864 + (size_t)4 * BB * HH * SS * DHD * 4)
                     : (float2*)(ws + 16777216);

  k_convert3<<<dim3(4096, 3), 256, 0, stream>>>(q, k, v, Xq);
  k_transpose4<<<dim3(32, 32, 4), dim3(32, 8), 0, stream>>>(Wq, Wk, Wv, Wo, Wtq);
  k_gemm_qkv<<<dim3(8, 32, 3), 256, 0, stream>>>(Xq, Xq + 4194304, Xq + 8388608,
                                                 Wtq, Qb, Kb, Vtb);
  k_attn<<<dim3(32, 16, 2 * P), 256, 0, stream>>>(Qb, Kb, Vtb, Opart, Ml, vl, part);
  if (big) k_merge<4><<<4096, 256, 0, stream>>>(Opart, Ml, vl, Ob);
  else     k_merge<1><<<4096, 256, 0, stream>>>(Opart, Ml, vl, Ob);
  k_gemm_wo<<<dim3(8, 64), 256, 0, stream>>>(Ob, Wto, (float*)d_out);
}

// Round 5
// 217.072 us; speedup vs baseline: 1.4169x; 1.3032x over previous
//
#include <hip/hip_runtime.h>
#include <stdint.h>

// Problem constants
#define BB 2
#define SS 2048
#define DD 1024
#define HH 16
#define DHD 64
#define MM (BB * SS)  // 4096

typedef unsigned short u16;
typedef unsigned int u32;
typedef __attribute__((ext_vector_type(8))) short bhalf8;   // 8 bf16 in 4 VGPRs
typedef __attribute__((ext_vector_type(4))) float floatx4;  // MFMA 16x16 accumulator
typedef __attribute__((ext_vector_type(2))) u32 u32x2;
typedef __attribute__((address_space(3))) u32 as3_u32;
typedef __attribute__((address_space(1))) u32 as1_u32;

__device__ __forceinline__ u16 f2bf(float f) {
  u32 u = __float_as_uint(f);
  u32 r = (u + 0x7FFFu + ((u >> 16) & 1u)) >> 16;  // RNE
  return (u16)r;
}

__device__ __forceinline__ u32 cvtpk_bf16(float lo, float hi) {
  u32 r;
  asm("v_cvt_pk_bf16_f32 %0, %1, %2" : "=v"(r) : "v"(lo), "v"(hi));
  return r;
}

__device__ __forceinline__ float exp2_fast(float x) {  // v_exp_f32 computes 2^x
  float r;
  asm("v_exp_f32 %0, %1" : "=v"(r) : "v"(x));
  return r;
}

// async global->LDS, 16B per lane; lds dest must be wave-uniform base (+lane*16 by HW)
__device__ __forceinline__ void gload16(const void* g, const void* l) {
  __builtin_amdgcn_global_load_lds((as1_u32*)(uintptr_t)g, (as3_u32*)(uintptr_t)l, 16, 0, 0);
}

// ---------------- fused fp32 -> bf16 convert for q,k,v (z-indexed) ----------------
__global__ void k_convert3(const float* __restrict__ q, const float* __restrict__ k,
                           const float* __restrict__ v, u16* __restrict__ out) {
  const int z = blockIdx.y;
  const float* src = (z == 0) ? q : (z == 1) ? k : v;
  const int i = blockIdx.x * 256 + threadIdx.x;  // grid.x*256 == 4M/4 exactly
  float4 val = ((const float4*)src)[i];
  ushort4 o;
  o.x = f2bf(val.x); o.y = f2bf(val.y); o.z = f2bf(val.z); o.w = f2bf(val.w);
  ((ushort4*)(out + (size_t)z * 4194304))[i] = o;
}

// ---------------- fused W[K][N] fp32 -> Wt[N][K] bf16 (z-indexed, scaled) ----------
// z==0 (Wq) folds 1/sqrt(DH) * log2(e) so attention scores come out in log2 units.
__global__ void k_transpose4(const float* __restrict__ Wq, const float* __restrict__ Wk,
                             const float* __restrict__ Wv, const float* __restrict__ Wo,
                             u16* __restrict__ Wt) {
  const int z = blockIdx.z;
  const float* W = (z == 0) ? Wq : (z == 1) ? Wk : (z == 2) ? Wv : Wo;
  const float sc = (z == 0) ? 0.18033688011112042f : 1.0f;  // 0.125 * log2(e)
  __shared__ u16 tile[32][33];
  const int tx = threadIdx.x, ty = threadIdx.y;  // (32, 8)
  const int n0 = blockIdx.x * 32, k0 = blockIdx.y * 32;
#pragma unroll
  for (int i = 0; i < 4; ++i)
    tile[ty + 8 * i][tx] = f2bf(W[(size_t)(k0 + ty + 8 * i) * DD + n0 + tx] * sc);
  __syncthreads();
  u16* dst = Wt + (size_t)z * 1048576;
#pragma unroll
  for (int i = 0; i < 4; ++i)
    dst[(size_t)(n0 + ty + 8 * i) * DD + k0 + tx] = tile[tx][ty + 8 * i];
}

// ---------------- fused QKV GEMM: z selects A/Bt/C; 128x128 tile, BK=32 --------------
__global__ __launch_bounds__(256, 2) void k_gemm_qkv(
    const u16* __restrict__ Xq, const u16* __restrict__ Xk, const u16* __restrict__ Xv,
    const u16* __restrict__ Wt, u16* __restrict__ Qb, u16* __restrict__ Kb,
    u16* __restrict__ Vtb) {
  const int z = blockIdx.z;
  const u16* A = (z == 0) ? Xq : (z == 1) ? Xk : Xv;
  const u16* Bt = Wt + (size_t)z * 1048576;
  __shared__ __attribute__((aligned(16))) u16 sA[2][128 * 32];
  __shared__ __attribute__((aligned(16))) u16 sB[2][128 * 32];
  const int t = threadIdx.x;
  const int w = t >> 6, lane = t & 63;
  const int lr = lane & 15, lg = lane >> 4;
  const int wr = w >> 1, wc = w & 1;
  const int row0 = blockIdx.y * 128, col0 = blockIdx.x * 128;

  const int srow = t >> 2;
  const int skoff = (t & 3) * 8;
  const u16* gA = A + (size_t)(row0 + srow) * DD + skoff;
  const u16* gB = Bt + (size_t)(col0 + srow) * DD + skoff;
  const int ldsbase = w * 512;

  floatx4 acc[4][4] = {};

  auto stage = [&](int buf, int kt) {
    const int ko = kt * 32;
    gload16(gA + ko, &sA[buf][ldsbase]);
    gload16(gA + ko + (size_t)64 * DD, &sA[buf][2048 + ldsbase]);
    gload16(gB + ko, &sB[buf][ldsbase]);
    gload16(gB + ko + (size_t)64 * DD, &sB[buf][2048 + ldsbase]);
  };

  int cur = 0;
  stage(0, 0);
  __syncthreads();
  for (int kt = 0; kt < 32; ++kt) {
    if (kt + 1 < 32) stage(cur ^ 1, kt + 1);
    bhalf8 af[4], bf[4];
#pragma unroll
    for (int m = 0; m < 4; ++m)
      af[m] = *(const bhalf8*)&sA[cur][(wr * 64 + m * 16 + lr) * 32 + lg * 8];
#pragma unroll
    for (int n = 0; n < 4; ++n)
      bf[n] = *(const bhalf8*)&sB[cur][(wc * 64 + n * 16 + lr) * 32 + lg * 8];
#pragma unroll
    for (int m = 0; m < 4; ++m)
#pragma unroll
      for (int n = 0; n < 4; ++n)
        acc[m][n] = __builtin_amdgcn_mfma_f32_16x16x32_bf16(af[m], bf[n], acc[m][n], 0, 0, 0);
    __syncthreads();
    cur ^= 1;
  }

#pragma unroll
  for (int m = 0; m < 4; ++m) {
#pragma unroll
    for (int n = 0; n < 4; ++n) {
      const int col = col0 + wc * 64 + n * 16 + lr;
      const int rowb = row0 + wr * 64 + m * 16 + lg * 4;
      if (z == 2) {
        // V^T layout: Vtb[(b*1024 + col)][s]
        const int bidx = rowb >> 11, s = rowb & (SS - 1);
        ushort4 pk;
        pk.x = f2bf(acc[m][n][0]); pk.y = f2bf(acc[m][n][1]);
        pk.z = f2bf(acc[m][n][2]); pk.w = f2bf(acc[m][n][3]);
        *(ushort4*)&Vtb[((size_t)bidx * 1024 + col) * SS + s] = pk;
      } else {
        u16* C = (z == 0) ? Qb : Kb;
#pragma unroll
        for (int r = 0; r < 4; ++r)
          C[(size_t)(rowb + r) * DD + col] = f2bf(acc[m][n][r]);
      }
    }
  }
}

// ---------------- Wo GEMM: 64x128 tile (512 blocks, 2/CU), fp32 out ------------------
__global__ __launch_bounds__(256, 2) void k_gemm_wo(
    const u16* __restrict__ A, const u16* __restrict__ Bt, float* __restrict__ C) {
  __shared__ __attribute__((aligned(16))) u16 sA[2][64 * 32];
  __shared__ __attribute__((aligned(16))) u16 sB[2][128 * 32];
  const int t = threadIdx.x;
  const int w = t >> 6, lane = t & 63;
  const int lr = lane & 15, lg = lane >> 4;
  const int wr = w >> 1, wc = w & 1;
  const int row0 = blockIdx.y * 64, col0 = blockIdx.x * 128;

  const int srow = t >> 2;
  const int skoff = (t & 3) * 8;
  const u16* gA = A + (size_t)(row0 + srow) * DD + skoff;
  const u16* gB = Bt + (size_t)(col0 + srow) * DD + skoff;
  const int ldsbase = w * 512;

  floatx4 acc[2][4] = {};

  auto stage = [&](int buf, int kt) {
    const int ko = kt * 32;
    gload16(gA + ko, &sA[buf][ldsbase]);
    gload16(gB + ko, &sB[buf][ldsbase]);
    gload16(gB + ko + (size_t)64 * DD, &sB[buf][2048 + ldsbase]);
  };

  int cur = 0;
  stage(0, 0);
  __syncthreads();
  for (int kt = 0; kt < 32; ++kt) {
    if (kt + 1 < 32) stage(cur ^ 1, kt + 1);
    bhalf8 af[2], bf[4];
#pragma unroll
    for (int m = 0; m < 2; ++m)
      af[m] = *(const bhalf8*)&sA[cur][(wr * 32 + m * 16 + lr) * 32 + lg * 8];
#pragma unroll
    for (int n = 0; n < 4; ++n)
      bf[n] = *(const bhalf8*)&sB[cur][(wc * 64 + n * 16 + lr) * 32 + lg * 8];
#pragma unroll
    for (int m = 0; m < 2; ++m)
#pragma unroll
      for (int n = 0; n < 4; ++n)
        acc[m][n] = __builtin_amdgcn_mfma_f32_16x16x32_bf16(af[m], bf[n], acc[m][n], 0, 0, 0);
    __syncthreads();
    cur ^= 1;
  }

#pragma unroll
  for (int m = 0; m < 2; ++m)
#pragma unroll
    for (int n = 0; n < 4; ++n) {
      const int col = col0 + wc * 64 + n * 16 + lr;
      const int rowb = row0 + wr * 32 + m * 16 + lg * 4;
#pragma unroll
      for (int r = 0; r < 4; ++r)
        C[(size_t)(rowb + r) * DD + col] = acc[m][n][r];
    }
}

// ---------------- flash attention v5 (LDS-staged shared K/V, split-KV, defer-max) ----
// grid (S/64, H, B*P), 256 threads = 4 waves, each wave owns 16 q-rows, KV tile = 64.
// K/V tiles staged ONCE per block into LDS via global_load_lds (double-buffered,
// XOR-swizzled: lds[row][c16] = G[row][c16 ^ (row&7)]) and shared by all 4 waves.
// Swapped QK^T: s[c][r] = S[key=c*16+lg*4+r][q=lr] in log2 units (scale folded in Wq).
// Softmax in-register per q-row; P via wave-private LDS; PV from LDS V-frags.
__global__ __launch_bounds__(256, 2) void k_attn(
    const u16* __restrict__ Q, const u16* __restrict__ K, const u16* __restrict__ Vt,
    float* __restrict__ Opart, float2* __restrict__ Ml,
    const int* __restrict__ valid_lens, const int part) {
  const int t = threadIdx.x;
  const int w = t >> 6, lane = t & 63;
  const int lr = lane & 15, lg = lane >> 4;
  const int h = blockIdx.y, z = blockIdx.z;
  const int b = z & 1, p = z >> 1;
  const int q0 = blockIdx.x * 64 + w * 16;
  const int vl = valid_lens[b];
  const int kbeg = p * part;
  if (kbeg >= vl) return;  // dead partition (uniform)
  const int kend = (vl < kbeg + part) ? vl : (kbeg + part);
  const int L = kend - kbeg;

  __shared__ __attribute__((aligned(16))) u16 kbuf[2][64 * 64];  // [key][dim] swizzled
  __shared__ __attribute__((aligned(16))) u16 vbuf[2][64 * 64];  // [d][key]  swizzled
  __shared__ __attribute__((aligned(16))) u16 p_lds[4][16 * 72]; // wave-private
  u16* pl = &p_lds[w][0];

  const u16* Qp = Q + ((size_t)(b * SS + q0 + lr)) * DD + h * DHD;
  const bhalf8 qf0 = *(const bhalf8*)(Qp + lg * 8);
  const bhalf8 qf1 = *(const bhalf8*)(Qp + 32 + lg * 8);

  // staging source (per-lane, pre-swizzled so linear LDS dest ends up swizzled)
  const int sub = lane >> 3;          // row-in-octet 0..7 (== row&7 of dest row)
  const int sc16 = (lane & 7) ^ sub;  // swizzled source col16
  const u16* ksrc = K + (size_t)(b * SS + kbeg + w * 16 + sub) * DD + h * DHD + sc16 * 8;
  const u16* vsrc = Vt + ((size_t)(b * HH + h) * DHD + w * 16 + sub) * SS + kbeg + sc16 * 8;

  auto stage = [&](int buf, int i) {
    const int sk0 = i * 64;
    gload16(ksrc + (size_t)sk0 * DD,       &kbuf[buf][(w * 16) * 64]);
    gload16(ksrc + (size_t)(sk0 + 8) * DD, &kbuf[buf][(w * 16 + 8) * 64]);
    gload16(vsrc + sk0,                    &vbuf[buf][(w * 16) * 64]);
    gload16(vsrc + (size_t)8 * SS + sk0,   &vbuf[buf][(w * 16 + 8) * 64]);
  };

  float mrun = -1e30f, lrun = 0.f;  // per-lane: stats of q-row (q0 + lr), log2 units
  floatx4 o[4] = {};                // o[dt]: C[q = lg*4+r][d = dt*16+lr]

  const int nblk = (L + 63) >> 6;
  const bool partial = (L & 63) != 0;
  const int swz = lr & 7;  // fragment-read swizzle (row&7 for rows c*16+lr / dt*16+lr)

  stage(0, 0);
  __syncthreads();

  int cb = 0;
  for (int i = 0; i < nblk; ++i) {
    if (i + 1 < nblk) stage(cb ^ 1, i + 1);
    const u16* kb = &kbuf[cb][0];
    const u16* vb = &vbuf[cb][0];
    // QK^T from LDS K-frags
    floatx4 s[4];
    __builtin_amdgcn_s_setprio(1);
#pragma unroll
    for (int c = 0; c < 4; ++c) {
      const bhalf8 kc0 = *(const bhalf8*)&kb[(c * 16 + lr) * 64 + ((lg ^ swz) * 8)];
      const bhalf8 kc1 = *(const bhalf8*)&kb[(c * 16 + lr) * 64 + (((lg + 4) ^ swz) * 8)];
      floatx4 zz = {0.f, 0.f, 0.f, 0.f};
      zz = __builtin_amdgcn_mfma_f32_16x16x32_bf16(kc0, qf0, zz, 0, 0, 0);
      s[c] = __builtin_amdgcn_mfma_f32_16x16x32_bf16(kc1, qf1, zz, 0, 0, 0);
    }
    __builtin_amdgcn_s_setprio(0);
    // mask tail keys (uniform branch; key index is per-reg)
    if (partial && i == nblk - 1) {
      const int sk0 = i * 64;
#pragma unroll
      for (int c = 0; c < 4; ++c)
#pragma unroll
        for (int r = 0; r < 4; ++r)
          if (sk0 + c * 16 + lg * 4 + r >= L) s[c][r] = -1e6f;
    }
    // row max: in-register tree + 2 cross-lane steps
    float tmax = fmaxf(fmaxf(fmaxf(s[0][0], s[0][1]), fmaxf(s[0][2], s[0][3])),
                       fmaxf(fmaxf(s[1][0], s[1][1]), fmaxf(s[1][2], s[1][3])));
    tmax = fmaxf(tmax, fmaxf(fmaxf(fmaxf(s[2][0], s[2][1]), fmaxf(s[2][2], s[2][3])),
                             fmaxf(fmaxf(s[3][0], s[3][1]), fmaxf(s[3][2], s[3][3]))));
    tmax = fmaxf(tmax, __shfl_xor(tmax, 16));
    tmax = fmaxf(tmax, __shfl_xor(tmax, 32));
    // defer-max: skip O-rescale while max growth <= 8 (log2 units; P bounded by 256)
    if (!__all(tmax <= mrun + 8.0f)) {
      const float nm = fmaxf(mrun, tmax);
      const float sc = exp2_fast(mrun - nm);
      mrun = nm;
      lrun *= sc;
      float scb[4];
#pragma unroll
      for (int r = 0; r < 4; ++r) scb[r] = __shfl(sc, lg * 4 + r);
#pragma unroll
      for (int dt = 0; dt < 4; ++dt)
#pragma unroll
        for (int r = 0; r < 4; ++r) o[dt][r] *= scb[r];
    }
    // p = exp2(s - m), row sum, pack to bf16 pairs
    float rs = 0.f;
    u32 pk[4][2];
#pragma unroll
    for (int c = 0; c < 4; ++c) {
      float p0 = exp2_fast(s[c][0] - mrun), p1 = exp2_fast(s[c][1] - mrun);
      float p2 = exp2_fast(s[c][2] - mrun), p3 = exp2_fast(s[c][3] - mrun);
      rs += (p0 + p1) + (p2 + p3);
      pk[c][0] = cvtpk_bf16(p0, p1);
      pk[c][1] = cvtpk_bf16(p2, p3);
    }
    rs += __shfl_xor(rs, 16);
    rs += __shfl_xor(rs, 32);
    lrun += rs;
    // P -> wave-private LDS: lane writes its own q-row (lr)
#pragma unroll
    for (int c = 0; c < 4; ++c) {
      u32x2 pr; pr.x = pk[c][0]; pr.y = pk[c][1];
      *(u32x2*)&pl[lr * 72 + c * 16 + lg * 4] = pr;
    }
    asm volatile("s_waitcnt lgkmcnt(0)" ::: "memory");  // in-wave write->read ordering
    const bhalf8 pa0 = *(const bhalf8*)&pl[lr * 72 + lg * 8];
    const bhalf8 pa1 = *(const bhalf8*)&pl[lr * 72 + 32 + lg * 8];
    // PV from LDS V-frags
    __builtin_amdgcn_s_setprio(1);
#pragma unroll
    for (int dt = 0; dt < 4; ++dt) {
      const bhalf8 vf0 = *(const bhalf8*)&vb[(dt * 16 + lr) * 64 + ((lg ^ swz) * 8)];
      const bhalf8 vf1 = *(const bhalf8*)&vb[(dt * 16 + lr) * 64 + (((lg + 4) ^ swz) * 8)];
      o[dt] = __builtin_amdgcn_mfma_f32_16x16x32_bf16(pa0, vf0, o[dt], 0, 0, 0);
      o[dt] = __builtin_amdgcn_mfma_f32_16x16x32_bf16(pa1, vf1, o[dt], 0, 0, 0);
    }
    __builtin_amdgcn_s_setprio(0);
    __syncthreads();  // staging of next tile drained + all waves done with cb
    cb ^= 1;
  }

  // epilogue: store unnormalized partial + (m, l)
  const size_t rowbase = ((size_t)(b * HH + h)) * SS + q0;
  const size_t pbase = (size_t)p * (BB * HH * SS);
#pragma unroll
  for (int dt = 0; dt < 4; ++dt)
#pragma unroll
    for (int r = 0; r < 4; ++r)
      Opart[(pbase + rowbase + lg * 4 + r) * DHD + dt * 16 + lr] = o[dt][r];
  if (lane < 16) {
    float2 ml; ml.x = mrun; ml.y = lrun;
    Ml[pbase + rowbase + lr] = ml;
  }
}

// ---------------- merge split-KV partials -> bf16 merged-head output -----------------
template <int P>
__global__ void k_merge(const float* __restrict__ Opart, const float2* __restrict__ Ml,
                        const int* __restrict__ valid_lens, u16* __restrict__ Ob) {
  const int t = threadIdx.x;
  const int rid = blockIdx.x * 16 + (t >> 4);  // [0, B*H*S)
  const int dc = t & 15;
  const int b = rid >> 15;
  const int h = (rid >> 11) & (HH - 1);
  const int s = rid & (SS - 1);
  const int vl = valid_lens[b];
  constexpr int part = SS / P;
  float m[P], l[P];
  float4 o4[P];
  bool live[P];
  float M = -1e30f;
#pragma unroll
  for (int p = 0; p < P; ++p) {
    live[p] = (p * part < vl);
    if (live[p]) {
      float2 ml = Ml[(size_t)p * (BB * HH * SS) + rid];
      m[p] = ml.x; l[p] = ml.y;
      o4[p] = *(const float4*)&Opart[((size_t)p * (BB * HH * SS) + rid) * DHD + dc * 4];
      M = fmaxf(M, m[p]);
    }
  }
  float L = 0.f;
  float4 acc = {0.f, 0.f, 0.f, 0.f};
#pragma unroll
  for (int p = 0; p < P; ++p)
    if (live[p]) {
      const float wgt = exp2_fast(m[p] - M);
      L += l[p] * wgt;
      acc.x += wgt * o4[p].x; acc.y += wgt * o4[p].y;
      acc.z += wgt * o4[p].z; acc.w += wgt * o4[p].w;
    }
  const float inv = 1.0f / L;
  ushort4 r;
  r.x = f2bf(acc.x * inv); r.y = f2bf(acc.y * inv);
  r.z = f2bf(acc.z * inv); r.w = f2bf(acc.w * inv);
  *(ushort4*)&Ob[((size_t)(b * SS + s)) * DD + h * DHD + dc * 4] = r;
}

extern "C" void kernel_launch(void* const* d_in, const int* in_sizes, int n_in,
                              void* d_out, int out_size, void* d_ws, size_t ws_size,
                              hipStream_t stream) {
  const float* q = (const float*)d_in[0];
  const float* k = (const float*)d_in[1];
  const float* v = (const float*)d_in[2];
  const int* vl = (const int*)d_in[3];
  const float* Wq = (const float*)d_in[4];
  const float* Wk = (const float*)d_in[5];
  const float* Wv = (const float*)d_in[6];
  const float* Wo = (const float*)d_in[7];

  char* ws = (char*)d_ws;
  u16* Xq  = (u16*)(ws + 0);          // 8 MiB each (dead after QKV GEMM)
  u16* Wtq = (u16*)(ws + 25165824);   // 2 MiB each: Wtq,Wtk,Wtv,Wto contiguous
  u16* Wto = (u16*)(ws + 31457280);
  u16* Qb  = (u16*)(ws + 33554432);   // 8 MiB each
  u16* Kb  = (u16*)(ws + 41943040);
  u16* Vtb = (u16*)(ws + 50331648);
  u16* Ob  = (u16*)(ws + 58720256);   // 8 MiB

  // split-KV partials: P=4 above 64MiB if workspace allows, else P=1 overlaying dead X
  const bool big = ws_size >= (size_t)134 * 1024 * 1024;
  const int P = big ? 4 : 1;
  const int part = SS / P;
  float* Opart = big ? (float*)(ws + 67108864) : (float*)(ws + 0);
  float2* Ml   = big ? (float2*)(ws + 67108864 + (size_t)4 * BB * HH * SS * DHD * 4)
                     : (float2*)(ws + 16777216);

  k_convert3<<<dim3(4096, 3), 256, 0, stream>>>(q, k, v, Xq);
  k_transpose4<<<dim3(32, 32, 4), dim3(32, 8), 0, stream>>>(Wq, Wk, Wv, Wo, Wtq);
  k_gemm_qkv<<<dim3(8, 32, 3), 256, 0, stream>>>(Xq, Xq + 4194304, Xq + 8388608,
                                                 Wtq, Qb, Kb, Vtb);
  k_attn<<<dim3(32, 16, 2 * P), 256, 0, stream>>>(Qb, Kb, Vtb, Opart, Ml, vl, part);
  if (big) k_merge<4><<<4096, 256, 0, stream>>>(Opart, Ml, vl, Ob);
  else     k_merge<1><<<4096, 256, 0, stream>>>(Opart, Ml, vl, Ob);
  k_gemm_wo<<<dim3(8, 64), 256, 0, stream>>>(Ob, Wto, (float*)d_out);
}

// Round 6
// 205.508 us; speedup vs baseline: 1.4966x; 1.0563x over previous
//
#include <hip/hip_runtime.h>
#include <stdint.h>

// Problem constants
#define BB 2
#define SS 2048
#define DD 1024
#define HH 16
#define DHD 64
#define MM (BB * SS)  // 4096

typedef unsigned short u16;
typedef unsigned int u32;
typedef __attribute__((ext_vector_type(8))) short bhalf8;   // 8 bf16 in 4 VGPRs
typedef __attribute__((ext_vector_type(4))) float floatx4;  // MFMA 16x16 accumulator
typedef __attribute__((ext_vector_type(2))) u32 u32x2;
typedef __attribute__((address_space(3))) u32 as3_u32;
typedef __attribute__((address_space(1))) u32 as1_u32;

__device__ __forceinline__ u16 f2bf(float f) {
  u32 u = __float_as_uint(f);
  u32 r = (u + 0x7FFFu + ((u >> 16) & 1u)) >> 16;  // RNE
  return (u16)r;
}

__device__ __forceinline__ u32 cvtpk_bf16(float lo, float hi) {
  u32 r;
  asm("v_cvt_pk_bf16_f32 %0, %1, %2" : "=v"(r) : "v"(lo), "v"(hi));
  return r;
}

__device__ __forceinline__ float exp2_fast(float x) {  // v_exp_f32 computes 2^x
  float r;
  asm("v_exp_f32 %0, %1" : "=v"(r) : "v"(x));
  return r;
}

// async global->LDS, 16B per lane; lds dest must be wave-uniform base (+lane*16 by HW)
__device__ __forceinline__ void gload16(const void* g, const void* l) {
  __builtin_amdgcn_global_load_lds((as1_u32*)(uintptr_t)g, (as3_u32*)(uintptr_t)l, 16, 0, 0);
}

// ---------------- fused fp32 -> bf16 convert for q,k,v (z-indexed) ----------------
__global__ void k_convert3(const float* __restrict__ q, const float* __restrict__ k,
                           const float* __restrict__ v, u16* __restrict__ out) {
  const int z = blockIdx.y;
  const float* src = (z == 0) ? q : (z == 1) ? k : v;
  const int i = blockIdx.x * 256 + threadIdx.x;  // grid.x*256 == 4M/4 exactly
  float4 val = ((const float4*)src)[i];
  ushort4 o;
  o.x = f2bf(val.x); o.y = f2bf(val.y); o.z = f2bf(val.z); o.w = f2bf(val.w);
  ((ushort4*)(out + (size_t)z * 4194304))[i] = o;
}

// ---------------- fused W[K][N] fp32 -> Wt[N][K] bf16 (z-indexed, scaled) ----------
// z==0 (Wq) folds 1/sqrt(DH) * log2(e) so attention scores come out in log2 units.
__global__ void k_transpose4(const float* __restrict__ Wq, const float* __restrict__ Wk,
                             const float* __restrict__ Wv, const float* __restrict__ Wo,
                             u16* __restrict__ Wt) {
  const int z = blockIdx.z;
  const float* W = (z == 0) ? Wq : (z == 1) ? Wk : (z == 2) ? Wv : Wo;
  const float sc = (z == 0) ? 0.18033688011112042f : 1.0f;  // 0.125 * log2(e)
  __shared__ u16 tile[32][33];
  const int tx = threadIdx.x, ty = threadIdx.y;  // (32, 8)
  const int n0 = blockIdx.x * 32, k0 = blockIdx.y * 32;
#pragma unroll
  for (int i = 0; i < 4; ++i)
    tile[ty + 8 * i][tx] = f2bf(W[(size_t)(k0 + ty + 8 * i) * DD + n0 + tx] * sc);
  __syncthreads();
  u16* dst = Wt + (size_t)z * 1048576;
#pragma unroll
  for (int i = 0; i < 4; ++i)
    dst[(size_t)(n0 + ty + 8 * i) * DD + k0 + tx] = tile[tx][ty + 8 * i];
}

// ---------------- fused QKV GEMM: 1D grid 768, XCD-swizzled; 128x128 tile, BK=32 -----
// id = r + 8*(a*8 + c): the 8 col-blocks (c) of group g=8a+r share id%8 -> same XCD,
// so each A row-panel is fetched into one XCD's L2 instead of all eight.
__global__ __launch_bounds__(256, 2) void k_gemm_qkv(
    const u16* __restrict__ Xq, const u16* __restrict__ Xk, const u16* __restrict__ Xv,
    const u16* __restrict__ Wt, u16* __restrict__ Qb, u16* __restrict__ Kb,
    u16* __restrict__ Vtb) {
  const int id = blockIdx.x;
  const int rr = id & 7, t8 = id >> 3;
  const int g = (t8 >> 3) * 8 + rr, c = t8 & 7;  // g in [0,96), c in [0,8)
  const int z = g / 32, by = g % 32, bx = c;
  const u16* A = (z == 0) ? Xq : (z == 1) ? Xk : Xv;
  const u16* Bt = Wt + (size_t)z * 1048576;
  __shared__ __attribute__((aligned(16))) u16 sA[2][128 * 32];
  __shared__ __attribute__((aligned(16))) u16 sB[2][128 * 32];
  const int t = threadIdx.x;
  const int w = t >> 6, lane = t & 63;
  const int lr = lane & 15, lg = lane >> 4;
  const int wr = w >> 1, wc = w & 1;
  const int row0 = by * 128, col0 = bx * 128;

  const int srow = t >> 2;
  const int skoff = (t & 3) * 8;
  const u16* gA = A + (size_t)(row0 + srow) * DD + skoff;
  const u16* gB = Bt + (size_t)(col0 + srow) * DD + skoff;
  const int ldsbase = w * 512;

  floatx4 acc[4][4] = {};

  auto stage = [&](int buf, int kt) {
    const int ko = kt * 32;
    gload16(gA + ko, &sA[buf][ldsbase]);
    gload16(gA + ko + (size_t)64 * DD, &sA[buf][2048 + ldsbase]);
    gload16(gB + ko, &sB[buf][ldsbase]);
    gload16(gB + ko + (size_t)64 * DD, &sB[buf][2048 + ldsbase]);
  };

  int cur = 0;
  stage(0, 0);
  __syncthreads();
  for (int kt = 0; kt < 32; ++kt) {
    if (kt + 1 < 32) stage(cur ^ 1, kt + 1);
    bhalf8 af[4], bf[4];
#pragma unroll
    for (int m = 0; m < 4; ++m)
      af[m] = *(const bhalf8*)&sA[cur][(wr * 64 + m * 16 + lr) * 32 + lg * 8];
#pragma unroll
    for (int n = 0; n < 4; ++n)
      bf[n] = *(const bhalf8*)&sB[cur][(wc * 64 + n * 16 + lr) * 32 + lg * 8];
#pragma unroll
    for (int m = 0; m < 4; ++m)
#pragma unroll
      for (int n = 0; n < 4; ++n)
        acc[m][n] = __builtin_amdgcn_mfma_f32_16x16x32_bf16(af[m], bf[n], acc[m][n], 0, 0, 0);
    __syncthreads();
    cur ^= 1;
  }

#pragma unroll
  for (int m = 0; m < 4; ++m) {
#pragma unroll
    for (int n = 0; n < 4; ++n) {
      const int col = col0 + wc * 64 + n * 16 + lr;
      const int rowb = row0 + wr * 64 + m * 16 + lg * 4;
      if (z == 2) {
        // V^T layout: Vtb[(b*1024 + col)][s]
        const int bidx = rowb >> 11, s = rowb & (SS - 1);
        ushort4 pk;
        pk.x = f2bf(acc[m][n][0]); pk.y = f2bf(acc[m][n][1]);
        pk.z = f2bf(acc[m][n][2]); pk.w = f2bf(acc[m][n][3]);
        *(ushort4*)&Vtb[((size_t)bidx * 1024 + col) * SS + s] = pk;
      } else {
        u16* C = (z == 0) ? Qb : Kb;
#pragma unroll
        for (int r = 0; r < 4; ++r)
          C[(size_t)(rowb + r) * DD + col] = f2bf(acc[m][n][r]);
      }
    }
  }
}

// ---------------- Wo GEMM: 1D grid 512, XCD-swizzled; 64x128 tile, fp32 out ----------
__global__ __launch_bounds__(256, 2) void k_gemm_wo(
    const u16* __restrict__ A, const u16* __restrict__ Bt, float* __restrict__ C) {
  const int id = blockIdx.x;
  const int rr = id & 7, t8 = id >> 3;
  const int g = (t8 >> 3) * 8 + rr, c = t8 & 7;  // g in [0,64) rows, c in [0,8) cols
  const int by = g, bx = c;
  __shared__ __attribute__((aligned(16))) u16 sA[2][64 * 32];
  __shared__ __attribute__((aligned(16))) u16 sB[2][128 * 32];
  const int t = threadIdx.x;
  const int w = t >> 6, lane = t & 63;
  const int lr = lane & 15, lg = lane >> 4;
  const int wr = w >> 1, wc = w & 1;
  const int row0 = by * 64, col0 = bx * 128;

  const int srow = t >> 2;
  const int skoff = (t & 3) * 8;
  const u16* gA = A + (size_t)(row0 + srow) * DD + skoff;
  const u16* gB = Bt + (size_t)(col0 + srow) * DD + skoff;
  const int ldsbase = w * 512;

  floatx4 acc[2][4] = {};

  auto stage = [&](int buf, int kt) {
    const int ko = kt * 32;
    gload16(gA + ko, &sA[buf][ldsbase]);
    gload16(gB + ko, &sB[buf][ldsbase]);
    gload16(gB + ko + (size_t)64 * DD, &sB[buf][2048 + ldsbase]);
  };

  int cur = 0;
  stage(0, 0);
  __syncthreads();
  for (int kt = 0; kt < 32; ++kt) {
    if (kt + 1 < 32) stage(cur ^ 1, kt + 1);
    bhalf8 af[2], bf[4];
#pragma unroll
    for (int m = 0; m < 2; ++m)
      af[m] = *(const bhalf8*)&sA[cur][(wr * 32 + m * 16 + lr) * 32 + lg * 8];
#pragma unroll
    for (int n = 0; n < 4; ++n)
      bf[n] = *(const bhalf8*)&sB[cur][(wc * 64 + n * 16 + lr) * 32 + lg * 8];
#pragma unroll
    for (int m = 0; m < 2; ++m)
#pragma unroll
      for (int n = 0; n < 4; ++n)
        acc[m][n] = __builtin_amdgcn_mfma_f32_16x16x32_bf16(af[m], bf[n], acc[m][n], 0, 0, 0);
    __syncthreads();
    cur ^= 1;
  }

#pragma unroll
  for (int m = 0; m < 2; ++m)
#pragma unroll
    for (int n = 0; n < 4; ++n) {
      const int col = col0 + wc * 64 + n * 16 + lr;
      const int rowb = row0 + wr * 32 + m * 16 + lg * 4;
#pragma unroll
      for (int r = 0; r < 4; ++r)
        C[(size_t)(rowb + r) * DD + col] = acc[m][n][r];
    }
}

// ---------------- flash attention v6 (LDS K/V, split-KV, XCD-swizzled grid) ----------
// 1D grid 1024*P, 256 threads = 4 waves, each wave owns 16 q-rows, KV tile = 64.
// id = r + 8*(a*32 + c): 32 q-blocks (c) of group g=8a+r (= one (h,b,p)) share id%8
// -> same XCD -> the K/V slice is fetched into one L2, reused by all 32 q-blocks.
__global__ __launch_bounds__(256, 2) void k_attn(
    const u16* __restrict__ Q, const u16* __restrict__ K, const u16* __restrict__ Vt,
    float* __restrict__ Opart, float2* __restrict__ Ml,
    const int* __restrict__ valid_lens, const int part) {
  const int id = blockIdx.x;
  const int rr = id & 7, tt = id >> 3;
  const int g = (tt >> 5) * 8 + rr, c = tt & 31;  // g = zi*16 + h
  const int h = g & 15, zi = g >> 4;
  const int b = zi & 1, p = zi >> 1;
  const int t = threadIdx.x;
  const int w = t >> 6, lane = t & 63;
  const int lr = lane & 15, lg = lane >> 4;
  const int q0 = c * 64 + w * 16;
  const int vl = valid_lens[b];
  const int kbeg = p * part;
  if (kbeg >= vl) return;  // dead partition (uniform)
  const int kend = (vl < kbeg + part) ? vl : (kbeg + part);
  const int L = kend - kbeg;

  __shared__ __attribute__((aligned(16))) u16 kbuf[2][64 * 64];  // [key][dim] swizzled
  __shared__ __attribute__((aligned(16))) u16 vbuf[2][64 * 64];  // [d][key]  swizzled
  __shared__ __attribute__((aligned(16))) u16 p_lds[4][16 * 72]; // wave-private
  u16* pl = &p_lds[w][0];

  const u16* Qp = Q + ((size_t)(b * SS + q0 + lr)) * DD + h * DHD;
  const bhalf8 qf0 = *(const bhalf8*)(Qp + lg * 8);
  const bhalf8 qf1 = *(const bhalf8*)(Qp + 32 + lg * 8);

  // staging source (per-lane, pre-swizzled so linear LDS dest ends up swizzled)
  const int sub = lane >> 3;          // row-in-octet 0..7 (== row&7 of dest row)
  const int sc16 = (lane & 7) ^ sub;  // swizzled source col16
  const u16* ksrc = K + (size_t)(b * SS + kbeg + w * 16 + sub) * DD + h * DHD + sc16 * 8;
  const u16* vsrc = Vt + ((size_t)(b * HH + h) * DHD + w * 16 + sub) * SS + kbeg + sc16 * 8;

  auto stage = [&](int buf, int i) {
    const int sk0 = i * 64;
    gload16(ksrc + (size_t)sk0 * DD,       &kbuf[buf][(w * 16) * 64]);
    gload16(ksrc + (size_t)(sk0 + 8) * DD, &kbuf[buf][(w * 16 + 8) * 64]);
    gload16(vsrc + sk0,                    &vbuf[buf][(w * 16) * 64]);
    gload16(vsrc + (size_t)8 * SS + sk0,   &vbuf[buf][(w * 16 + 8) * 64]);
  };

  float mrun = -1e30f, lrun = 0.f;  // per-lane: stats of q-row (q0 + lr), log2 units
  floatx4 o[4] = {};                // o[dt]: C[q = lg*4+r][d = dt*16+lr]

  const int nblk = (L + 63) >> 6;
  const bool partial = (L & 63) != 0;
  const int swz = lr & 7;  // fragment-read swizzle (row&7 for rows c*16+lr / dt*16+lr)

  stage(0, 0);
  __syncthreads();

  int cb = 0;
  for (int i = 0; i < nblk; ++i) {
    if (i + 1 < nblk) stage(cb ^ 1, i + 1);
    const u16* kb = &kbuf[cb][0];
    const u16* vb = &vbuf[cb][0];
    // QK^T from LDS K-frags
    floatx4 s[4];
    __builtin_amdgcn_s_setprio(1);
#pragma unroll
    for (int cc = 0; cc < 4; ++cc) {
      const bhalf8 kc0 = *(const bhalf8*)&kb[(cc * 16 + lr) * 64 + ((lg ^ swz) * 8)];
      const bhalf8 kc1 = *(const bhalf8*)&kb[(cc * 16 + lr) * 64 + (((lg + 4) ^ swz) * 8)];
      floatx4 zz = {0.f, 0.f, 0.f, 0.f};
      zz = __builtin_amdgcn_mfma_f32_16x16x32_bf16(kc0, qf0, zz, 0, 0, 0);
      s[cc] = __builtin_amdgcn_mfma_f32_16x16x32_bf16(kc1, qf1, zz, 0, 0, 0);
    }
    __builtin_amdgcn_s_setprio(0);
    // mask tail keys (uniform branch; key index is per-reg)
    if (partial && i == nblk - 1) {
      const int sk0 = i * 64;
#pragma unroll
      for (int cc = 0; cc < 4; ++cc)
#pragma unroll
        for (int r = 0; r < 4; ++r)
          if (sk0 + cc * 16 + lg * 4 + r >= L) s[cc][r] = -1e6f;
    }
    // row max: in-register tree + 2 cross-lane steps
    float tmax = fmaxf(fmaxf(fmaxf(s[0][0], s[0][1]), fmaxf(s[0][2], s[0][3])),
                       fmaxf(fmaxf(s[1][0], s[1][1]), fmaxf(s[1][2], s[1][3])));
    tmax = fmaxf(tmax, fmaxf(fmaxf(fmaxf(s[2][0], s[2][1]), fmaxf(s[2][2], s[2][3])),
                             fmaxf(fmaxf(s[3][0], s[3][1]), fmaxf(s[3][2], s[3][3]))));
    tmax = fmaxf(tmax, __shfl_xor(tmax, 16));
    tmax = fmaxf(tmax, __shfl_xor(tmax, 32));
    // defer-max: skip O-rescale while max growth <= 8 (log2 units; P bounded by 256)
    if (!__all(tmax <= mrun + 8.0f)) {
      const float nm = fmaxf(mrun, tmax);
      const float sc = exp2_fast(mrun - nm);
      mrun = nm;
      lrun *= sc;
      float scb[4];
#pragma unroll
      for (int r = 0; r < 4; ++r) scb[r] = __shfl(sc, lg * 4 + r);
#pragma unroll
      for (int dt = 0; dt < 4; ++dt)
#pragma unroll
        for (int r = 0; r < 4; ++r) o[dt][r] *= scb[r];
    }
    // p = exp2(s - m), row sum, pack to bf16 pairs
    float rs = 0.f;
    u32 pk[4][2];
#pragma unroll
    for (int cc = 0; cc < 4; ++cc) {
      float p0 = exp2_fast(s[cc][0] - mrun), p1 = exp2_fast(s[cc][1] - mrun);
      float p2 = exp2_fast(s[cc][2] - mrun), p3 = exp2_fast(s[cc][3] - mrun);
      rs += (p0 + p1) + (p2 + p3);
      pk[cc][0] = cvtpk_bf16(p0, p1);
      pk[cc][1] = cvtpk_bf16(p2, p3);
    }
    rs += __shfl_xor(rs, 16);
    rs += __shfl_xor(rs, 32);
    lrun += rs;
    // P -> wave-private LDS: lane writes its own q-row (lr)
#pragma unroll
    for (int cc = 0; cc < 4; ++cc) {
      u32x2 pr; pr.x = pk[cc][0]; pr.y = pk[cc][1];
      *(u32x2*)&pl[lr * 72 + cc * 16 + lg * 4] = pr;
    }
    asm volatile("s_waitcnt lgkmcnt(0)" ::: "memory");  // in-wave write->read ordering
    const bhalf8 pa0 = *(const bhalf8*)&pl[lr * 72 + lg * 8];
    const bhalf8 pa1 = *(const bhalf8*)&pl[lr * 72 + 32 + lg * 8];
    // PV from LDS V-frags
    __builtin_amdgcn_s_setprio(1);
#pragma unroll
    for (int dt = 0; dt < 4; ++dt) {
      const bhalf8 vf0 = *(const bhalf8*)&vb[(dt * 16 + lr) * 64 + ((lg ^ swz) * 8)];
      const bhalf8 vf1 = *(const bhalf8*)&vb[(dt * 16 + lr) * 64 + (((lg + 4) ^ swz) * 8)];
      o[dt] = __builtin_amdgcn_mfma_f32_16x16x32_bf16(pa0, vf0, o[dt], 0, 0, 0);
      o[dt] = __builtin_amdgcn_mfma_f32_16x16x32_bf16(pa1, vf1, o[dt], 0, 0, 0);
    }
    __builtin_amdgcn_s_setprio(0);
    __syncthreads();  // staging of next tile drained + all waves done with cb
    cb ^= 1;
  }

  // epilogue: store unnormalized partial + (m, l)
  const size_t rowbase = ((size_t)(b * HH + h)) * SS + q0;
  const size_t pbase = (size_t)p * (BB * HH * SS);
#pragma unroll
  for (int dt = 0; dt < 4; ++dt)
#pragma unroll
    for (int r = 0; r < 4; ++r)
      Opart[(pbase + rowbase + lg * 4 + r) * DHD + dt * 16 + lr] = o[dt][r];
  if (lane < 16) {
    float2 ml; ml.x = mrun; ml.y = lrun;
    Ml[pbase + rowbase + lr] = ml;
  }
}

// ---------------- merge split-KV partials -> bf16 merged-head output -----------------
template <int P>
__global__ void k_merge(const float* __restrict__ Opart, const float2* __restrict__ Ml,
                        const int* __restrict__ valid_lens, u16* __restrict__ Ob) {
  const int t = threadIdx.x;
  const int rid = blockIdx.x * 16 + (t >> 4);  // [0, B*H*S)
  const int dc = t & 15;
  const int b = rid >> 15;
  const int h = (rid >> 11) & (HH - 1);
  const int s = rid & (SS - 1);
  const int vl = valid_lens[b];
  constexpr int part = SS / P;
  float m[P], l[P];
  float4 o4[P];
  bool live[P];
  float M = -1e30f;
#pragma unroll
  for (int p = 0; p < P; ++p) {
    live[p] = (p * part < vl);
    if (live[p]) {
      float2 ml = Ml[(size_t)p * (BB * HH * SS) + rid];
      m[p] = ml.x; l[p] = ml.y;
      o4[p] = *(const float4*)&Opart[((size_t)p * (BB * HH * SS) + rid) * DHD + dc * 4];
      M = fmaxf(M, m[p]);
    }
  }
  float L = 0.f;
  float4 acc = {0.f, 0.f, 0.f, 0.f};
#pragma unroll
  for (int p = 0; p < P; ++p)
    if (live[p]) {
      const float wgt = exp2_fast(m[p] - M);
      L += l[p] * wgt;
      acc.x += wgt * o4[p].x; acc.y += wgt * o4[p].y;
      acc.z += wgt * o4[p].z; acc.w += wgt * o4[p].w;
    }
  const float inv = 1.0f / L;
  ushort4 r;
  r.x = f2bf(acc.x * inv); r.y = f2bf(acc.y * inv);
  r.z = f2bf(acc.z * inv); r.w = f2bf(acc.w * inv);
  *(ushort4*)&Ob[((size_t)(b * SS + s)) * DD + h * DHD + dc * 4] = r;
}

extern "C" void kernel_launch(void* const* d_in, const int* in_sizes, int n_in,
                              void* d_out, int out_size, void* d_ws, size_t ws_size,
                              hipStream_t stream) {
  const float* q = (const float*)d_in[0];
  const float* k = (const float*)d_in[1];
  const float* v = (const float*)d_in[2];
  const int* vl = (const int*)d_in[3];
  const float* Wq = (const float*)d_in[4];
  const float* Wk = (const float*)d_in[5];
  const float* Wv = (const float*)d_in[6];
  const float* Wo = (const float*)d_in[7];

  char* ws = (char*)d_ws;
  u16* Xq  = (u16*)(ws + 0);          // 8 MiB each (dead after QKV GEMM)
  u16* Wtq = (u16*)(ws + 25165824);   // 2 MiB each: Wtq,Wtk,Wtv,Wto contiguous
  u16* Wto = (u16*)(ws + 31457280);
  u16* Qb  = (u16*)(ws + 33554432);   // 8 MiB each
  u16* Kb  = (u16*)(ws + 41943040);
  u16* Vtb = (u16*)(ws + 50331648);
  u16* Ob  = (u16*)(ws + 58720256);   // 8 MiB

  // split-KV partials: P=2 above 64MiB if workspace allows, else P=1 overlaying dead X
  const bool big = ws_size >= (size_t)134 * 1024 * 1024;
  const int P = big ? 2 : 1;
  const int part = SS / P;
  float* Opart = big ? (float*)(ws + 67108864) : (float*)(ws + 0);
  float2* Ml   = big ? (float2*)(ws + 67108864 + (size_t)2 * BB * HH * SS * DHD * 4)
                     : (float2*)(ws + 16777216);

  k_convert3<<<dim3(4096, 3), 256, 0, stream>>>(q, k, v, Xq);
  k_transpose4<<<dim3(32, 32, 4), dim3(32, 8), 0, stream>>>(Wq, Wk, Wv, Wo, Wtq);
  k_gemm_qkv<<<768, 256, 0, stream>>>(Xq, Xq + 4194304, Xq + 8388608, Wtq, Qb, Kb, Vtb);
  k_attn<<<1024 * P, 256, 0, stream>>>(Qb, Kb, Vtb, Opart, Ml, vl, part);
  if (big) k_merge<2><<<4096, 256, 0, stream>>>(Opart, Ml, vl, Ob);
  else     k_merge<1><<<4096, 256, 0, stream>>>(Opart, Ml, vl, Ob);
  k_gemm_wo<<<512, 256, 0, stream>>>(Ob, Wto, (float*)d_out);
}